// Round 1
// baseline (537.814 us; speedup 1.0000x reference)
//
#include <hip/hip_runtime.h>
#include <math.h>

#define EPS 1e-6f

// ws layout (floats):
//   h      @ 0       [2][1024]
//   qkv    @ 2048    5 layers x [2][3072]   (q|k|v concatenated per row)
//   ao     @ 32768   5 layers x [2][1024]   (attention output, pre-Wo)
//   gu     @ 43008   5 layers x [2][2][4096] (s, gate/up, f)
//   lastn  @ 124928  [1024]

// ---------------- init: zero accumulators + build h ----------------
__global__ void init_kernel(const float* __restrict__ past_hidden,
                            const float* __restrict__ codec_emb,
                            const int* __restrict__ tok,
                            float* __restrict__ ws,
                            float* __restrict__ logits)
{
    size_t idx = (size_t)blockIdx.x * blockDim.x + threadIdx.x;
    size_t stride = (size_t)gridDim.x * blockDim.x;
    for (size_t i = idx; i < 30720; i += stride) ws[2048 + i] = 0.f;   // qkv x5
    for (size_t i = idx; i < 81920; i += stride) ws[43008 + i] = 0.f;  // gu x5
    for (size_t i = idx; i < 30720; i += stride) logits[i] = 0.f;      // logits out
    int t = tok[0];
    for (size_t i = idx; i < 1024; i += stride) {
        ws[i]        = past_hidden[i];
        ws[1024 + i] = codec_emb[(size_t)t * 1024 + i];
    }
}

// ---------------- generic split-K GEMV with optional fused RMSNorm ----------------
// x[S][D] @ W[D][N] -> atomicAdd out[z][s][N-slice]
// grid: (N/256, D/64, nz). block: 256.
// If W1 != nullptr: z picks among {W0,W1,W2}. Else W = W0 + z*w_zstride.
template <int S>
__global__ __launch_bounds__(256) void gemv_rms(
    const float* __restrict__ hbuf,   // [S][D]
    const float* __restrict__ nw,     // [D] rmsnorm weight, or nullptr
    const float* __restrict__ W0,
    const float* __restrict__ W1,
    const float* __restrict__ W2,
    size_t w_zstride,
    float* __restrict__ out,
    int out_sstride, int out_zstride,
    int D, int N)
{
    __shared__ float xs[S * 1024];
    __shared__ float red[S * 1024];
    __shared__ float tot[S];
    const int t = threadIdx.x;

    const float* W;
    if (W1) W = (blockIdx.z == 0) ? W0 : ((blockIdx.z == 1) ? W1 : W2);
    else    W = W0 + (size_t)blockIdx.z * w_zstride;
    float* outz = out + (size_t)blockIdx.z * out_zstride;

    if (nw) {
        float ss[S];
#pragma unroll
        for (int s = 0; s < S; ++s) ss[s] = 0.f;
        for (int dd = t; dd < D; dd += 256) {
#pragma unroll
            for (int s = 0; s < S; ++s) {
                float v = hbuf[s * D + dd];
                xs[s * 1024 + dd] = v;
                ss[s] += v * v;
            }
        }
#pragma unroll
        for (int s = 0; s < S; ++s) {
            red[t] = ss[s]; __syncthreads();
            for (int off = 128; off >= 1; off >>= 1) {
                if (t < off) red[t] += red[t + off];
                __syncthreads();
            }
            if (t == 0) tot[s] = red[0];
            __syncthreads();
        }
        float sc[S];
#pragma unroll
        for (int s = 0; s < S; ++s) sc[s] = rsqrtf(tot[s] / (float)D + EPS);
        for (int dd = t; dd < D; dd += 256) {
            float wv = nw[dd];
#pragma unroll
            for (int s = 0; s < S; ++s)
                xs[s * 1024 + dd] = xs[s * 1024 + dd] * sc[s] * wv;
        }
        __syncthreads();
    } else {
        for (int dd = t; dd < D; dd += 256) {
#pragma unroll
            for (int s = 0; s < S; ++s) xs[s * 1024 + dd] = hbuf[s * D + dd];
        }
        __syncthreads();
    }

    const int lane = t & 63;
    const int dp = t >> 6;             // 4-way split of the 64-row K chunk
    const int j = blockIdx.x * 256 + lane * 4;
    const int d0 = blockIdx.y * 64 + dp * 16;

    float acc[S][4];
#pragma unroll
    for (int s = 0; s < S; ++s) { acc[s][0] = acc[s][1] = acc[s][2] = acc[s][3] = 0.f; }
#pragma unroll
    for (int i = 0; i < 16; ++i) {
        int dd = d0 + i;
        float4 w4 = *reinterpret_cast<const float4*>(W + (size_t)dd * N + j);
#pragma unroll
        for (int s = 0; s < S; ++s) {
            float xv = xs[s * 1024 + dd];
            acc[s][0] += xv * w4.x; acc[s][1] += xv * w4.y;
            acc[s][2] += xv * w4.z; acc[s][3] += xv * w4.w;
        }
    }
    __syncthreads();
#pragma unroll
    for (int s = 0; s < S; ++s)
#pragma unroll
        for (int c = 0; c < 4; ++c)
            red[(dp * S + s) * 256 + lane * 4 + c] = acc[s][c];
    __syncthreads();
    for (int o = t; o < S * 256; o += 256) {
        int s = o >> 8;
        int col = o & 255;
        float sum = 0.f;
#pragma unroll
        for (int dp2 = 0; dp2 < 4; ++dp2) sum += red[(dp2 * S + s) * 256 + col];
        atomicAdd(outz + (size_t)s * out_sstride + blockIdx.x * 256 + col, sum);
    }
}

// ---------------- attention: q/k norm + rope + 2x2 softmax + V, writes kv cache ----------------
__global__ void attn_kernel(const float* __restrict__ qkv,   // [2][3072]
                            const float* __restrict__ qnw,   // [128]
                            const float* __restrict__ knw,   // [128]
                            float* __restrict__ ao,          // [2][1024]
                            float* __restrict__ kvc)         // layer kv: k at 0, v at 2048
{
    const int h = blockIdx.x;   // 8 heads
    const int d = threadIdx.x;  // 128 threads
    __shared__ float rbuf[128];
    __shared__ float qb[2][128], kb[2][128];

    float q[2], k[2], v[2];
#pragma unroll
    for (int s = 0; s < 2; ++s) {
        q[s] = qkv[s * 3072 +        h * 128 + d];
        k[s] = qkv[s * 3072 + 1024 + h * 128 + d];
        v[s] = qkv[s * 3072 + 2048 + h * 128 + d];
    }
    auto bred = [&](float val) -> float {
        rbuf[d] = val; __syncthreads();
        for (int off = 64; off >= 1; off >>= 1) {
            if (d < off) rbuf[d] += rbuf[d + off];
            __syncthreads();
        }
        float r = rbuf[0]; __syncthreads();
        return r;
    };
    float qs0 = bred(q[0] * q[0]);
    float qs1 = bred(q[1] * q[1]);
    float ks0 = bred(k[0] * k[0]);
    float ks1 = bred(k[1] * k[1]);
    float qsc[2] = { rsqrtf(qs0 / 128.f + EPS), rsqrtf(qs1 / 128.f + EPS) };
    float ksc[2] = { rsqrtf(ks0 / 128.f + EPS), rsqrtf(ks1 / 128.f + EPS) };
#pragma unroll
    for (int s = 0; s < 2; ++s) {
        qb[s][d] = q[s] * qsc[s] * qnw[d];
        kb[s][d] = k[s] * ksc[s] * knw[d];
    }
    __syncthreads();
    // RoPE: inv_freq = 10000^(-(d%64)/64), angle = pos * inv_freq
    float invf = powf(10000.f, -(float)(d & 63) / 64.f);
    float qr[2], kr[2];
#pragma unroll
    for (int s = 0; s < 2; ++s) {
        float ang = (float)s * invf;
        float c = cosf(ang), si = sinf(ang);
        float qrot = (d < 64) ? -qb[s][d + 64] : qb[s][d - 64];
        float krot = (d < 64) ? -kb[s][d + 64] : kb[s][d - 64];
        qr[s] = qb[s][d] * c + qrot * si;
        kr[s] = kb[s][d] * c + krot * si;
    }
    // kv cache: (1,H,S,HD), k block then v block
#pragma unroll
    for (int s = 0; s < 2; ++s) {
        kvc[h * 256 + s * 128 + d]        = kr[s];
        kvc[2048 + h * 256 + s * 128 + d] = v[s];
    }
    float p00 = bred(qr[0] * kr[0]);
    float p01 = bred(qr[0] * kr[1]);
    float p10 = bred(qr[1] * kr[0]);
    float p11 = bred(qr[1] * kr[1]);
    const float scale = 0.08838834764831845f; // 1/sqrt(128)
    float s00 = p00 * scale, s01 = p01 * scale - 1e9f;
    float m0 = fmaxf(s00, s01);
    float e0 = expf(s00 - m0), e1 = expf(s01 - m0);
    float in0 = 1.f / (e0 + e1);
    float w00 = e0 * in0, w01 = e1 * in0;
    float s10 = p10 * scale, s11 = p11 * scale;
    float m1 = fmaxf(s10, s11);
    float f0 = expf(s10 - m1), f1 = expf(s11 - m1);
    float in1 = 1.f / (f0 + f1);
    float w10 = f0 * in1, w11 = f1 * in1;

    ao[0 * 1024 + h * 128 + d] = w00 * v[0] + w01 * v[1];
    ao[1 * 1024 + h * 128 + d] = w10 * v[0] + w11 * v[1];
}

// ---------------- down-proj GEMV with fused silu(gate)*up, residual atomicAdd into h ----------------
// grid: (1024/256=4, 4096/64=64). block 256.
__global__ __launch_bounds__(256) void gemv_down(
    const float* __restrict__ gu,  // [s][2][4096]
    const float* __restrict__ W,   // [4096][1024]
    float* __restrict__ out)       // h [2][1024]
{
    __shared__ float a[2][64];
    __shared__ float red[2048];
    const int t = threadIdx.x;
    const int d0 = blockIdx.y * 64;
    if (t < 128) {
        int s = t >> 6, f = d0 + (t & 63);
        float g = gu[s * 8192 + f];
        float u = gu[s * 8192 + 4096 + f];
        float sg = g / (1.f + expf(-g));   // silu
        a[s][t & 63] = sg * u;
    }
    __syncthreads();
    const int lane = t & 63;
    const int dp = t >> 6;
    const int j = blockIdx.x * 256 + lane * 4;
    float acc[2][4] = {{0.f,0.f,0.f,0.f},{0.f,0.f,0.f,0.f}};
#pragma unroll
    for (int i = 0; i < 16; ++i) {
        int dl = dp * 16 + i;
        int dd = d0 + dl;
        float4 w4 = *reinterpret_cast<const float4*>(W + (size_t)dd * 1024 + j);
#pragma unroll
        for (int s = 0; s < 2; ++s) {
            float xv = a[s][dl];
            acc[s][0] += xv * w4.x; acc[s][1] += xv * w4.y;
            acc[s][2] += xv * w4.z; acc[s][3] += xv * w4.w;
        }
    }
#pragma unroll
    for (int s = 0; s < 2; ++s)
#pragma unroll
        for (int c = 0; c < 4; ++c)
            red[(dp * 2 + s) * 256 + lane * 4 + c] = acc[s][c];
    __syncthreads();
    for (int o = t; o < 512; o += 256) {
        int s = o >> 8, col = o & 255;
        float sum = 0.f;
#pragma unroll
        for (int dp2 = 0; dp2 < 4; ++dp2) sum += red[(dp2 * 2 + s) * 256 + col];
        atomicAdd(out + s * 1024 + blockIdx.x * 256 + col, sum);
    }
}

// ---------------- final rmsnorm of last token ----------------
__global__ void final_norm_kernel(const float* __restrict__ h,
                                  const float* __restrict__ w,
                                  float* __restrict__ outx)
{
    __shared__ float rbuf[256];
    __shared__ float tot;
    int t = threadIdx.x;
    float ss = 0.f;
    for (int dd = t; dd < 1024; dd += 256) { float v = h[1024 + dd]; ss += v * v; }
    rbuf[t] = ss; __syncthreads();
    for (int off = 128; off >= 1; off >>= 1) {
        if (t < off) rbuf[t] += rbuf[t + off];
        __syncthreads();
    }
    if (t == 0) tot = rbuf[0];
    __syncthreads();
    float sc = rsqrtf(tot / 1024.f + EPS);
    for (int dd = t; dd < 1024; dd += 256) outx[dd] = h[1024 + dd] * sc * w[dd];
}

extern "C" void kernel_launch(void* const* d_in, const int* in_sizes, int n_in,
                              void* d_out, int out_size, void* d_ws, size_t ws_size,
                              hipStream_t stream)
{
    const float* past_hidden = (const float*)d_in[0];
    const int*   cb0         = (const int*)d_in[1];
    const float* codec_emb   = (const float*)d_in[2];
    const float* Wq  = (const float*)d_in[3];
    const float* Wk  = (const float*)d_in[4];
    const float* Wv  = (const float*)d_in[5];
    const float* Wo  = (const float*)d_in[6];
    const float* qnw = (const float*)d_in[7];
    const float* knw = (const float*)d_in[8];
    const float* ln1 = (const float*)d_in[9];
    const float* ln2 = (const float*)d_in[10];
    const float* Wg  = (const float*)d_in[11];
    const float* Wu  = (const float*)d_in[12];
    const float* Wd  = (const float*)d_in[13];
    const float* fnw = (const float*)d_in[14];
    const float* lmh = (const float*)d_in[15];

    float* out = (float*)d_out;
    float* ws  = (float*)d_ws;
    float* h      = ws;             // 2048
    float* qkvb   = ws + 2048;      // 5*6144
    float* aob    = ws + 32768;     // 5*2048
    float* gub    = ws + 43008;     // 5*16384
    float* lastn  = ws + 124928;    // 1024
    float* logits = out;            // 30720
    float* kvc    = out + 30720;    // 20480

    init_kernel<<<256, 256, 0, stream>>>(past_hidden, codec_emb, cb0, ws, logits);

    for (int l = 0; l < 5; ++l) {
        const float* wq = Wq + (size_t)l * 1024 * 1024;
        const float* wk = Wk + (size_t)l * 1024 * 1024;
        const float* wv = Wv + (size_t)l * 1024 * 1024;
        const float* wo = Wo + (size_t)l * 1024 * 1024;
        const float* wg = Wg + (size_t)l * 1024 * 4096;
        const float* wu = Wu + (size_t)l * 1024 * 4096;
        const float* wd = Wd + (size_t)l * 4096 * 1024;
        float* qkv = qkvb + (size_t)l * 6144;
        float* ao  = aob  + (size_t)l * 2048;
        float* gu  = gub  + (size_t)l * 16384;

        // QKV projection with fused rmsnorm(ln1): out[s][z*1024 + j]
        gemv_rms<2><<<dim3(4, 16, 3), 256, 0, stream>>>(
            h, ln1 + l * 1024, wq, wk, wv, 0, qkv, 3072, 1024, 1024, 1024);
        // attention + kv cache write
        attn_kernel<<<8, 128, 0, stream>>>(qkv, qnw + l * 128, knw + l * 128, ao,
                                           kvc + (size_t)(2 * l) * 2048);
        // O projection, residual-added into h (h still holds res)
        gemv_rms<2><<<dim3(4, 16, 1), 256, 0, stream>>>(
            ao, nullptr, wo, nullptr, nullptr, 0, h, 1024, 0, 1024, 1024);
        // gate & up with fused rmsnorm(ln2): out[s][z*4096 + f]
        gemv_rms<2><<<dim3(16, 16, 2), 256, 0, stream>>>(
            h, ln2 + l * 1024, wg, wu, wu, 0, gu, 8192, 4096, 1024, 4096);
        // down proj with fused silu*up, residual-added into h
        gemv_down<<<dim3(4, 64), 256, 0, stream>>>(gu, wd, h);
    }

    final_norm_kernel<<<1, 256, 0, stream>>>(h, fnw, lastn);
    // lm heads: 15 x (1024 x 2048), logits[n][v]
    gemv_rms<1><<<dim3(8, 16, 15), 256, 0, stream>>>(
        lastn, nullptr, lmh, nullptr, nullptr, (size_t)1024 * 2048,
        logits, 2048, 2048, 1024, 2048);
}